// Round 1
// 452.776 us; speedup vs baseline: 1.0007x; 1.0007x over previous
//
#include <hip/hip_runtime.h>
#include <math.h>

// Problem constants
#define B_ 4
#define L_ 1024
#define N_ 2048
#define VDIM_ 512
#define LDIM_ 768
#define HID_ 512
#define H_ 8
#define HD_ 64
#define SCALE_ 0.125f

typedef __bf16 bf16;
typedef __bf16 bf16x4 __attribute__((ext_vector_type(4)));
typedef __bf16 bf16x8 __attribute__((ext_vector_type(8)));
typedef float f32x4 __attribute__((ext_vector_type(4)));

// Async global->LDS, 16B per lane. LDS dest = wave-uniform base + lane*16.
__device__ __forceinline__ void async_cp16(const bf16* g, bf16* l) {
    __builtin_amdgcn_global_load_lds(
        (const __attribute__((address_space(1))) unsigned int*)g,
        (__attribute__((address_space(3))) unsigned int*)l, 16, 0, 0);
}

// ---------------------------------------------------------------------------
// Fused converts: x, vfeats, Wq, Wkv -> bf16, Wproj -> hi/lo split, 1 launch.
// Ranges are block-aligned (1024 elems/block) so branches are block-uniform.
// ---------------------------------------------------------------------------
#define XE_   2097152   // B*L*VDIM
#define VFE_  6291456   // B*N*LDIM
#define WQE_  262144    // HID*VDIM
#define WKVE_ 786432    // 2*HID*LDIM
#define WPE_  262144    // VDIM*HID
__global__ void cvt_all(const float* __restrict__ x, const float* __restrict__ vf,
                        const float* __restrict__ wq, const float* __restrict__ wkv,
                        const float* __restrict__ wp,
                        bf16* __restrict__ xb, bf16* __restrict__ vfb,
                        bf16* __restrict__ wqb, bf16* __restrict__ wkvb,
                        bf16* __restrict__ wph, bf16* __restrict__ wpl)
{
    int e = (blockIdx.x * 256 + threadIdx.x) * 4;
    if (e < XE_ + VFE_ + WQE_ + WKVE_) {
        const float* src; bf16* dst; int off;
        if (e < XE_)                        { src = x;   dst = xb;   off = 0; }
        else if (e < XE_ + VFE_)            { src = vf;  dst = vfb;  off = XE_; }
        else if (e < XE_ + VFE_ + WQE_)     { src = wq;  dst = wqb;  off = XE_ + VFE_; }
        else                                { src = wkv; dst = wkvb; off = XE_ + VFE_ + WQE_; }
        int i = e - off;
        float4 v = *(const float4*)(src + i);
        bf16x4 o;
        o[0] = (bf16)v.x; o[1] = (bf16)v.y; o[2] = (bf16)v.z; o[3] = (bf16)v.w;
        *(bf16x4*)(dst + i) = o;
    } else {
        int i = e - (XE_ + VFE_ + WQE_ + WKVE_);
        float4 v = *(const float4*)(wp + i);
        bf16x4 hh, ll;
        float vv[4] = {v.x, v.y, v.z, v.w};
        #pragma unroll
        for (int j = 0; j < 4; ++j) {
            bf16 hb = (bf16)vv[j];
            hh[j] = hb;
            ll[j] = (bf16)(vv[j] - (float)hb);
        }
        *(bf16x4*)(wph + i) = hh;
        *(bf16x4*)(wpl + i) = ll;
    }
}

// ---------------------------------------------------------------------------
// Plain bf16 MFMA GEMM: C[M,N](bf16) = A[M,K](bf16) @ W[N,K](bf16)^T
// BK=64. 4 waves in 2x2; wave tile (BM/2) x (BN/2). LDS chunk-XOR swizzle.
// ---------------------------------------------------------------------------
template<int BM, int BN>
__global__ __launch_bounds__(256)
void gemm_bf16(const bf16* __restrict__ A, const bf16* __restrict__ W,
               bf16* __restrict__ C, int M, int N, int K)
{
    __shared__ bf16 As[BM * 64];
    __shared__ bf16 Ws[BN * 64];
    const int t = threadIdx.x, l = t & 63, wv = t >> 6;
    const int n0 = blockIdx.x * BN, m0 = blockIdx.y * BM;
    const int wm = (wv >> 1) * (BM / 2), wn = (wv & 1) * (BN / 2);
    constexpr int TI = BM / 32, TJ = BN / 32;
    const int lq = l & 15, qd = l >> 4, swz = l & 7;

    f32x4 acc[TI][TJ];
    #pragma unroll
    for (int i = 0; i < TI; ++i)
        #pragma unroll
        for (int j = 0; j < TJ; ++j)
            #pragma unroll
            for (int r = 0; r < 4; ++r) acc[i][j][r] = 0.f;

    for (int kt = 0; kt < K; kt += 64) {
        __syncthreads();
        for (int it = wv; it < BM / 8; it += 4) {
            int r = it * 8 + (l >> 3);
            int c = (l & 7) ^ (r & 7);
            async_cp16(A + (size_t)(m0 + r) * K + kt + c * 8, &As[it * 512]);
        }
        for (int it = wv; it < BN / 8; it += 4) {
            int r = it * 8 + (l >> 3);
            int c = (l & 7) ^ (r & 7);
            async_cp16(W + (size_t)(n0 + r) * K + kt + c * 8, &Ws[it * 512]);
        }
        __syncthreads();
        #pragma unroll
        for (int ks = 0; ks < 2; ++ks) {
            bf16x8 af[TI], wf[TJ];
            #pragma unroll
            for (int i = 0; i < TI; ++i) {
                int row = wm + i * 16 + lq;
                af[i] = *(const bf16x8*)&As[row * 64 + ((ks * 4 + qd) ^ swz) * 8];
            }
            #pragma unroll
            for (int j = 0; j < TJ; ++j) {
                int row = wn + j * 16 + lq;
                wf[j] = *(const bf16x8*)&Ws[row * 64 + ((ks * 4 + qd) ^ swz) * 8];
            }
            #pragma unroll
            for (int i = 0; i < TI; ++i)
                #pragma unroll
                for (int j = 0; j < TJ; ++j)
                    acc[i][j] = __builtin_amdgcn_mfma_f32_16x16x32_bf16(
                        af[i], wf[j], acc[i][j], 0, 0, 0);
        }
    }
    #pragma unroll
    for (int i = 0; i < TI; ++i)
        #pragma unroll
        for (int j = 0; j < TJ; ++j)
            #pragma unroll
            for (int r = 0; r < 4; ++r) {
                int row = m0 + wm + i * 16 + qd * 4 + r;
                int col = n0 + wn + j * 16 + lq;
                C[(size_t)row * N + col] = (bf16)acc[i][j][r];
            }
}

// ---------------------------------------------------------------------------
// Projection GEMM (2-term split weights): Cf = A @ (Wh+Wl)^T + bias, fp32 out.
// BM=64, BN=64, BK=64. Grid 8x64 = 512 blocks.
// ---------------------------------------------------------------------------
__global__ __launch_bounds__(256)
void gemm_proj(const bf16* __restrict__ A, const bf16* __restrict__ Wh,
               const bf16* __restrict__ Wl, const float* __restrict__ bias,
               float* __restrict__ Cf, int M, int N, int K)
{
    __shared__ bf16 sA[64 * 64];
    __shared__ bf16 sWh[64 * 64], sWl[64 * 64];
    const int t = threadIdx.x, l = t & 63, wv = t >> 6;
    const int n0 = blockIdx.x * 64, m0 = blockIdx.y * 64;
    const int wm = (wv >> 1) * 32, wn = (wv & 1) * 32;
    const int lq = l & 15, qd = l >> 4, swz = l & 7;

    f32x4 acc[2][2];
    #pragma unroll
    for (int i = 0; i < 2; ++i)
        #pragma unroll
        for (int j = 0; j < 2; ++j)
            #pragma unroll
            for (int r = 0; r < 4; ++r) acc[i][j][r] = 0.f;

    for (int kt = 0; kt < K; kt += 64) {
        __syncthreads();
        for (int it = wv; it < 8; it += 4) {
            int r = it * 8 + (l >> 3);
            int c = (l & 7) ^ (r & 7);
            async_cp16(A  + (size_t)(m0 + r) * K + kt + c * 8, &sA[it * 512]);
            size_t go = (size_t)(n0 + r) * K + kt + c * 8;
            async_cp16(Wh + go, &sWh[it * 512]);
            async_cp16(Wl + go, &sWl[it * 512]);
        }
        __syncthreads();
        #pragma unroll
        for (int ks = 0; ks < 2; ++ks) {
            bf16x8 af[2], wh[2], wl[2];
            #pragma unroll
            for (int i = 0; i < 2; ++i) {
                int off = (wm + i * 16 + lq) * 64 + ((ks * 4 + qd) ^ swz) * 8;
                af[i] = *(const bf16x8*)&sA[off];
            }
            #pragma unroll
            for (int j = 0; j < 2; ++j) {
                int off = (wn + j * 16 + lq) * 64 + ((ks * 4 + qd) ^ swz) * 8;
                wh[j] = *(const bf16x8*)&sWh[off];
                wl[j] = *(const bf16x8*)&sWl[off];
            }
            #pragma unroll
            for (int i = 0; i < 2; ++i)
                #pragma unroll
                for (int j = 0; j < 2; ++j) {
                    acc[i][j] = __builtin_amdgcn_mfma_f32_16x16x32_bf16(af[i], wh[j], acc[i][j], 0, 0, 0);
                    acc[i][j] = __builtin_amdgcn_mfma_f32_16x16x32_bf16(af[i], wl[j], acc[i][j], 0, 0, 0);
                }
        }
    }
    #pragma unroll
    for (int i = 0; i < 2; ++i)
        #pragma unroll
        for (int j = 0; j < 2; ++j) {
            int col = n0 + wn + j * 16 + lq;
            float bb = bias[col];
            #pragma unroll
            for (int r = 0; r < 4; ++r) {
                int row = m0 + wm + i * 16 + qd * 4 + r;
                Cf[(size_t)row * N + col] = acc[i][j][r] + bb;
            }
        }
}

// ---------------------------------------------------------------------------
// Transpose v-part of kv into vT[(b*H+h)*HD + d][n]  (bf16)
// ---------------------------------------------------------------------------
__global__ __launch_bounds__(256)
void transpose_v(const bf16* __restrict__ kv, bf16* __restrict__ vT)
{
    __shared__ bf16 T[64 * 64];
    const int t = threadIdx.x;
    const int bid = blockIdx.x;
    const int nt = bid & 31, h = (bid >> 5) & 7, b = bid >> 8;
    const int n0 = nt * 64;
    for (int g = t; g < 512; g += 256) {
        int r = g >> 3, c = g & 7;
        bf16x8 v = *(const bf16x8*)(kv + (size_t)(b * N_ + n0 + r) * (2 * HID_) +
                                    HID_ + h * HD_ + c * 8);
        *(bf16x8*)&T[r * 64 + (c ^ (r & 7)) * 8] = v;
    }
    __syncthreads();
    for (int g = t; g < 512; g += 256) {
        int d = g >> 3, kg = g & 7;
        bf16x8 ov;
        #pragma unroll
        for (int jj = 0; jj < 8; ++jj) {
            int key = kg * 8 + jj;
            ov[jj] = T[key * 64 + (((d >> 3) ^ (key & 7))) * 8 + (d & 7)];
        }
        *(bf16x8*)&vT[(size_t)((b * H_ + h) * HD_ + d) * N_ + n0 + kg * 8] = ov;
    }
}

// ---------------------------------------------------------------------------
// Flash attention, bf16 MFMA. Block = 64 Q rows (4 waves x 16), KT=64 keys.
// Software-pipelined: K/V double-buffered via global_load_lds, mask prefetched
// one tile ahead into registers. End-of-iter sync = counted vmcnt(16) + raw
// s_barrier (m201 pattern): the 16 mask loads for tile t+1 stay in flight
// across the barrier; the 4 oldest retired VMEM ops are this wave's gll.
// ---------------------------------------------------------------------------
#define KT_ 64
#define NT_ 32      // N_/KT_
#define PST 72      // P LDS row stride (bf16): lq*PST spreads banks, 16B-aligned reads
__global__ __launch_bounds__(256)
void attn_mfma(const bf16* __restrict__ q, const bf16* __restrict__ kv,
               const bf16* __restrict__ vT, const float* __restrict__ mask,
               bf16* __restrict__ ao)
{
    __shared__ bf16 Ks[2][64 * 64];    // [buf][key][dim] chunk-XOR swizzle (16 KB)
    __shared__ bf16 Vs[2][64 * 64];    // [buf][dim][key] chunk-XOR swizzle (16 KB)
    __shared__ bf16 Pa[4][16 * PST];   // per-wave P [qrow][key] (9 KB)
    const int t = threadIdx.x, l = t & 63, wv = t >> 6;
    // XCD-chunked swizzle: 512 blocks = 8 XCDs x 64; each XCD L2 then holds
    // 4 contiguous (b,h) K/V working sets (~2 MB) instead of 32 (16 MB thrash).
    const int bid0 = blockIdx.x;
    const int bid = (bid0 & 7) * 64 + (bid0 >> 3);
    const int lt = bid & 15, h = (bid >> 4) & 7, b = bid >> 7;
    const int l0 = lt * 64;
    const int lq = l & 15, qd = l >> 4, swz = l & 7;
    const int sr = l >> 3;                       // stage: row-in-8 per lane
    const int sc8 = ((l & 7) ^ sr) * 8;          // stage: swizzled chunk offset

    // Q A-fragments (held in regs for all iterations)
    bf16x8 qf[2];
    {
        const bf16* qb = q + (size_t)(b * L_ + l0 + wv * 16 + lq) * HID_ + h * HD_ + qd * 8;
        qf[0] = *(const bf16x8*)qb;
        qf[1] = *(const bf16x8*)(qb + 32);
    }

    f32x4 o[4];
    #pragma unroll
    for (int j = 0; j < 4; ++j)
        #pragma unroll
        for (int r = 0; r < 4; ++r) o[j][r] = 0.f;
    float m_run[4], l_run[4];
    #pragma unroll
    for (int r = 0; r < 4; ++r) { m_run[r] = -1e30f; l_run[r] = 0.f; }

    const bf16* kb = kv + (size_t)(b * N_) * (2 * HID_) + h * HD_;
    const bf16* vb = vT + (size_t)((b * H_ + h) * HD_) * N_;
    const size_t mrow0 = (size_t)((b * H_ + h) * L_ + l0 + wv * 16);
    bf16* Paw = &Pa[wv][0];

    float mkA[4][4], mkB[4][4];

// 4 global_load_lds per wave (2 K + 2 V), issued as the oldest VMEM of the iter
#define STAGE(BUF, NTILE) do {                                                  \
    const int nb_ = (NTILE) * KT_;                                              \
    _Pragma("unroll")                                                           \
    for (int it_ = 0; it_ < 2; ++it_) {                                         \
        int r_ = (wv + it_ * 4) * 8 + sr;                                       \
        async_cp16(kb + (size_t)(nb_ + r_) * (2 * HID_) + sc8,                  \
                   &Ks[BUF][(wv + it_ * 4) * 512]);                             \
    }                                                                           \
    _Pragma("unroll")                                                           \
    for (int it_ = 0; it_ < 2; ++it_) {                                         \
        int r_ = (wv + it_ * 4) * 8 + sr;                                       \
        async_cp16(vb + (size_t)r_ * N_ + nb_ + sc8,                            \
                   &Vs[BUF][(wv + it_ * 4) * 512]);                             \
    }                                                                           \
} while (0)

// 16 dword loads per lane -> registers (C-fragment layout of S)
#define MASKLOAD(DST, NTILE) do {                                               \
    const int nb_ = (NTILE) * KT_;                                              \
    _Pragma("unroll")                                                           \
    for (int jj = 0; jj < 4; ++jj)                                              \
        _Pragma("unroll")                                                       \
        for (int r = 0; r < 4; ++r)                                             \
            DST[jj][r] = mask[(mrow0 + qd * 4 + r) * N_ + nb_ + jj * 16 + lq];  \
} while (0)

#define ATTN_ITER(NTI, CB, NB, MKC, MKN) do {                                   \
    if ((NTI) + 1 < NT_) {                                                      \
        STAGE(NB, (NTI) + 1);                                                   \
        __builtin_amdgcn_sched_barrier(0);                                      \
        MASKLOAD(MKN, (NTI) + 1);                                               \
        __builtin_amdgcn_sched_barrier(0);                                      \
    }                                                                           \
    /* S = Q K^T (8 MFMA) on Ks[CB] */                                          \
    f32x4 s[4];                                                                 \
    _Pragma("unroll")                                                           \
    for (int jj = 0; jj < 4; ++jj)                                              \
        _Pragma("unroll")                                                       \
        for (int r = 0; r < 4; ++r) s[jj][r] = 0.f;                             \
    _Pragma("unroll")                                                           \
    for (int ks = 0; ks < 2; ++ks)                                              \
        _Pragma("unroll")                                                       \
        for (int jj = 0; jj < 4; ++jj) {                                        \
            bf16x8 kf = *(const bf16x8*)&Ks[CB][(jj * 16 + lq) * 64 +           \
                                               ((ks * 4 + qd) ^ swz) * 8];      \
            s[jj] = __builtin_amdgcn_mfma_f32_16x16x32_bf16(qf[ks], kf, s[jj], 0, 0, 0); \
        }                                                                       \
    _Pragma("unroll")                                                           \
    for (int jj = 0; jj < 4; ++jj)                                              \
        _Pragma("unroll")                                                       \
        for (int r = 0; r < 4; ++r)                                             \
            s[jj][r] = fmaf(s[jj][r], SCALE_, MKC[jj][r]);                      \
    /* online softmax (row = qd*4+r; reduce over 16 lanes sharing qd) */        \
    float alpha[4], mnew[4];                                                    \
    _Pragma("unroll")                                                           \
    for (int r = 0; r < 4; ++r) {                                               \
        float mx = fmaxf(fmaxf(s[0][r], s[1][r]), fmaxf(s[2][r], s[3][r]));     \
        _Pragma("unroll")                                                       \
        for (int d2 = 1; d2 < 16; d2 <<= 1) mx = fmaxf(mx, __shfl_xor(mx, d2)); \
        mnew[r] = fmaxf(m_run[r], mx);                                          \
        alpha[r] = __expf(m_run[r] - mnew[r]);                                  \
        m_run[r] = mnew[r];                                                     \
    }                                                                           \
    _Pragma("unroll")                                                           \
    for (int r = 0; r < 4; ++r) {                                               \
        float ss = 0.f;                                                         \
        _Pragma("unroll")                                                       \
        for (int jj = 0; jj < 4; ++jj) {                                        \
            float p = __expf(s[jj][r] - mnew[r]);                               \
            Paw[(qd * 4 + r) * PST + jj * 16 + lq] = (bf16)p;                   \
            ss += p;                                                            \
        }                                                                       \
        _Pragma("unroll")                                                       \
        for (int d2 = 1; d2 < 16; d2 <<= 1) ss += __shfl_xor(ss, d2);           \
        l_run[r] = l_run[r] * alpha[r] + ss;                                    \
    }                                                                           \
    asm volatile("s_waitcnt lgkmcnt(0)" ::: "memory");                          \
    __builtin_amdgcn_sched_barrier(0);                                          \
    /* O = O*alpha + P V (8 MFMA) on Vs[CB] */                                  \
    _Pragma("unroll")                                                           \
    for (int jj = 0; jj < 4; ++jj)                                              \
        _Pragma("unroll")                                                       \
        for (int r = 0; r < 4; ++r) o[jj][r] *= alpha[r];                       \
    _Pragma("unroll")                                                           \
    for (int ks = 0; ks < 2; ++ks) {                                            \
        bf16x8 pf = *(const bf16x8*)&Paw[lq * PST + ks * 32 + qd * 8];          \
        _Pragma("unroll")                                                       \
        for (int jj = 0; jj < 4; ++jj) {                                        \
            bf16x8 vf = *(const bf16x8*)&Vs[CB][(jj * 16 + lq) * 64 +           \
                                               ((ks * 4 + qd) ^ swz) * 8];      \
            o[jj] = __builtin_amdgcn_mfma_f32_16x16x32_bf16(pf, vf, o[jj], 0, 0, 0); \
        }                                                                       \
    }                                                                           \
    /* end-of-iter: own stage(nxt) done (mask loads stay in flight), waves sync */ \
    __builtin_amdgcn_sched_barrier(0);                                          \
    asm volatile("s_waitcnt vmcnt(16)" ::: "memory");                           \
    __builtin_amdgcn_s_barrier();                                               \
    __builtin_amdgcn_sched_barrier(0);                                          \
} while (0)

    // prologue: stage tile 0 into buf 0, mask tile 0 into mkA
    STAGE(0, 0);
    MASKLOAD(mkA, 0);
    __syncthreads();

    #pragma unroll 1
    for (int nt2 = 0; nt2 < NT_; nt2 += 2) {
        ATTN_ITER(nt2,     0, 1, mkA, mkB);
        ATTN_ITER(nt2 + 1, 1, 0, mkB, mkA);
    }
#undef ATTN_ITER
#undef MASKLOAD
#undef STAGE

    // epilogue: normalize + plain bf16 store
    #pragma unroll
    for (int jj = 0; jj < 4; ++jj)
        #pragma unroll
        for (int r = 0; r < 4; ++r) {
            int row = b * L_ + l0 + wv * 16 + qd * 4 + r;
            int col = h * HD_ + jj * 16 + lq;
            ao[(size_t)row * HID_ + col] = (bf16)(o[jj][r] / l_run[r]);
        }
}

// ---------------------------------------------------------------------------
extern "C" void kernel_launch(void* const* d_in, const int* in_sizes, int n_in,
                              void* d_out, int out_size, void* d_ws, size_t ws_size,
                              hipStream_t stream)
{
    const float* x      = (const float*)d_in[0];  // [B,L,VDIM]
    const float* vfeats = (const float*)d_in[1];  // [B,N,LDIM]
    const float* mask   = (const float*)d_in[2];  // [B,H,L,N]
    const float* Wq     = (const float*)d_in[3];  // [HID,VDIM]
    const float* Wkv    = (const float*)d_in[4];  // [2*HID,LDIM]
    const float* Wproj  = (const float*)d_in[5];  // [VDIM,HID]
    const float* bproj  = (const float*)d_in[6];  // [VDIM]
    float* out = (float*)d_out;                   // [B,L,VDIM] fp32

    // Workspace layout (~53.5 MB, no aliasing)
    char* ws = (char*)d_ws;
    bf16* xb   = (bf16*)(ws);                     // 4 MB
    bf16* vfb  = (bf16*)(ws + 4194304);           // 12 MB
    bf16* wqb  = (bf16*)(ws + 16777216);          // 0.5 MB
    bf16* wkvb = (bf16*)(ws + 17301504);          // 1.5 MB
    bf16* wph  = (bf16*)(ws + 18874368);          // 0.5 MB
    bf16* wpl  = (bf16*)(ws + 19398656);          // 0.5 MB
    bf16* qb   = (bf16*)(ws + 19922944);          // 4 MB
    bf16* kvb  = (bf16*)(ws + 24117248);          // 16 MB
    bf16* vTb  = (bf16*)(ws + 40894464);          // 8 MB
    bf16* aob  = (bf16*)(ws + 49283072);          // 4 MB

    dim3 blk(256);
    // fused converts (1 launch)
    cvt_all<<<dim3((XE_ + VFE_ + WQE_ + WKVE_ + WPE_) / 1024), blk, 0, stream>>>(
        x, vfeats, Wq, Wkv, Wproj, xb, vfb, wqb, wkvb, wph, wpl);
    // q = x @ Wq^T : [4096,512]   grid 8x64 = 512 blocks
    gemm_bf16<64, 64><<<dim3(HID_ / 64, B_ * L_ / 64), blk, 0, stream>>>(
        xb, wqb, qb, B_ * L_, HID_, VDIM_);
    // kv = vfeats @ Wkv^T : [8192,1024]   128x128 tiles, grid 8x64 = 512 blocks
    gemm_bf16<128, 128><<<dim3(2 * HID_ / 128, B_ * N_ / 128), blk, 0, stream>>>(
        vfb, wkvb, kvb, B_ * N_, 2 * HID_, LDIM_);
    // v-part -> vT[(b,h,d)][n]
    transpose_v<<<dim3(B_ * H_ * (N_ / 64)), blk, 0, stream>>>(kvb, vTb);
    // attention (512 blocks, pipelined)
    attn_mfma<<<dim3(B_ * H_ * (L_ / 64)), blk, 0, stream>>>(qb, kvb, vTb, mask, aob);
    // out = attn_out @ (Wproj hi+lo)^T + bproj   grid 8x64 = 512 blocks
    gemm_proj<<<dim3(VDIM_ / 64, B_ * L_ / 64), blk, 0, stream>>>(
        aob, wph, wpl, bproj, out, B_ * L_, VDIM_, HID_);
}

// Round 2
// 446.928 us; speedup vs baseline: 1.0138x; 1.0131x over previous
//
#include <hip/hip_runtime.h>
#include <math.h>

// Problem constants
#define B_ 4
#define L_ 1024
#define N_ 2048
#define VDIM_ 512
#define LDIM_ 768
#define HID_ 512
#define H_ 8
#define HD_ 64
#define SCALE_ 0.125f

typedef __bf16 bf16;
typedef __bf16 bf16x4 __attribute__((ext_vector_type(4)));
typedef __bf16 bf16x8 __attribute__((ext_vector_type(8)));
typedef float f32x4 __attribute__((ext_vector_type(4)));

// Async global->LDS, 16B per lane. LDS dest = wave-uniform base + lane*16.
__device__ __forceinline__ void async_cp16(const bf16* g, bf16* l) {
    __builtin_amdgcn_global_load_lds(
        (const __attribute__((address_space(1))) unsigned int*)g,
        (__attribute__((address_space(3))) unsigned int*)l, 16, 0, 0);
}

// ---------------------------------------------------------------------------
// Fused converts: x, vfeats, Wq, Wkv -> bf16, Wproj -> hi/lo split, 1 launch.
// Ranges are block-aligned (1024 elems/block) so branches are block-uniform.
// ---------------------------------------------------------------------------
#define XE_   2097152   // B*L*VDIM
#define VFE_  6291456   // B*N*LDIM
#define WQE_  262144    // HID*VDIM
#define WKVE_ 786432    // 2*HID*LDIM
#define WPE_  262144    // VDIM*HID
__global__ void cvt_all(const float* __restrict__ x, const float* __restrict__ vf,
                        const float* __restrict__ wq, const float* __restrict__ wkv,
                        const float* __restrict__ wp,
                        bf16* __restrict__ xb, bf16* __restrict__ vfb,
                        bf16* __restrict__ wqb, bf16* __restrict__ wkvb,
                        bf16* __restrict__ wph, bf16* __restrict__ wpl)
{
    int e = (blockIdx.x * 256 + threadIdx.x) * 4;
    if (e < XE_ + VFE_ + WQE_ + WKVE_) {
        const float* src; bf16* dst; int off;
        if (e < XE_)                        { src = x;   dst = xb;   off = 0; }
        else if (e < XE_ + VFE_)            { src = vf;  dst = vfb;  off = XE_; }
        else if (e < XE_ + VFE_ + WQE_)     { src = wq;  dst = wqb;  off = XE_ + VFE_; }
        else                                { src = wkv; dst = wkvb; off = XE_ + VFE_ + WQE_; }
        int i = e - off;
        float4 v = *(const float4*)(src + i);
        bf16x4 o;
        o[0] = (bf16)v.x; o[1] = (bf16)v.y; o[2] = (bf16)v.z; o[3] = (bf16)v.w;
        *(bf16x4*)(dst + i) = o;
    } else {
        int i = e - (XE_ + VFE_ + WQE_ + WKVE_);
        float4 v = *(const float4*)(wp + i);
        bf16x4 hh, ll;
        float vv[4] = {v.x, v.y, v.z, v.w};
        #pragma unroll
        for (int j = 0; j < 4; ++j) {
            bf16 hb = (bf16)vv[j];
            hh[j] = hb;
            ll[j] = (bf16)(vv[j] - (float)hb);
        }
        *(bf16x4*)(wph + i) = hh;
        *(bf16x4*)(wpl + i) = ll;
    }
}

// ---------------------------------------------------------------------------
// Shared GEMM main loop: acc += A[m0:m0+BM, kt] @ W[n0:n0+BN, kt]^T over K.
// BK=64, 4 waves in 2x2, LDS chunk-XOR swizzle, gll-16B staging.
// ---------------------------------------------------------------------------
template<int BM, int BN>
__device__ __forceinline__ void gemm_core(
    const bf16* __restrict__ A, const bf16* __restrict__ W,
    bf16* __restrict__ As, bf16* __restrict__ Ws,
    int m0, int n0, int K, int l, int wv,
    f32x4 (&acc)[BM / 32][BN / 32])
{
    constexpr int TI = BM / 32, TJ = BN / 32;
    const int lq = l & 15, qd = l >> 4, swz = l & 7;
    const int wm = (wv >> 1) * (BM / 2), wn = (wv & 1) * (BN / 2);

    #pragma unroll
    for (int i = 0; i < TI; ++i)
        #pragma unroll
        for (int j = 0; j < TJ; ++j)
            #pragma unroll
            for (int r = 0; r < 4; ++r) acc[i][j][r] = 0.f;

    for (int kt = 0; kt < K; kt += 64) {
        __syncthreads();
        for (int it = wv; it < BM / 8; it += 4) {
            int r = it * 8 + (l >> 3);
            int c = (l & 7) ^ (r & 7);
            async_cp16(A + (size_t)(m0 + r) * K + kt + c * 8, &As[it * 512]);
        }
        for (int it = wv; it < BN / 8; it += 4) {
            int r = it * 8 + (l >> 3);
            int c = (l & 7) ^ (r & 7);
            async_cp16(W + (size_t)(n0 + r) * K + kt + c * 8, &Ws[it * 512]);
        }
        __syncthreads();
        #pragma unroll
        for (int ks = 0; ks < 2; ++ks) {
            bf16x8 af[TI], wf[TJ];
            #pragma unroll
            for (int i = 0; i < TI; ++i) {
                int row = wm + i * 16 + lq;
                af[i] = *(const bf16x8*)&As[row * 64 + ((ks * 4 + qd) ^ swz) * 8];
            }
            #pragma unroll
            for (int j = 0; j < TJ; ++j) {
                int row = wn + j * 16 + lq;
                wf[j] = *(const bf16x8*)&Ws[row * 64 + ((ks * 4 + qd) ^ swz) * 8];
            }
            #pragma unroll
            for (int i = 0; i < TI; ++i)
                #pragma unroll
                for (int j = 0; j < TJ; ++j)
                    acc[i][j] = __builtin_amdgcn_mfma_f32_16x16x32_bf16(
                        af[i], wf[j], acc[i][j], 0, 0, 0);
        }
    }
}

// ---------------------------------------------------------------------------
// Fused q + kv GEMM, one launch, 1536 blocks (bijective XCD-chunked).
//   blocks [0,512):    q  = x @ Wq^T        [4096,512]  tiles 64x64
//   blocks [512,1536): kv = vfeats @ Wkv^T  [8192,1024] tiles 128x64
// kv v-part blocks (n0 >= HID) write V TRANSPOSED into vT via LDS bounce
// (replaces the separate transpose_v kernel; v-part of kvb is never written).
// ---------------------------------------------------------------------------
#define TST 136   // transpose bounce row stride (bf16)
__global__ __launch_bounds__(256)
void gemm_qkv(const bf16* __restrict__ xb, const bf16* __restrict__ wqb,
              bf16* __restrict__ qb,
              const bf16* __restrict__ vfb, const bf16* __restrict__ wkvb,
              bf16* __restrict__ kvb, bf16* __restrict__ vTb)
{
    __shared__ bf16 pool[128 * 64 + 64 * 64];   // 24 KB: As (16K) + Ws (8K)
    bf16* As = pool;
    bf16* Ws = pool + 128 * 64;
    const int t = threadIdx.x, l = t & 63, wv = t >> 6;
    const int lq = l & 15, qd = l >> 4;
    // 1536 blocks = 8 XCDs x 192 (1536 % 8 == 0 -> simple chunking bijective)
    const int o = blockIdx.x;
    const int bid = (o & 7) * 192 + (o >> 3);

    if (bid < 512) {
        // ---- q role ----
        const int n0 = (bid & 7) * 64, m0 = (bid >> 3) * 64;
        f32x4 acc[2][2];
        gemm_core<64, 64>(xb, wqb, As, Ws, m0, n0, VDIM_, l, wv, acc);
        const int wm = (wv >> 1) * 32, wn = (wv & 1) * 32;
        #pragma unroll
        for (int i = 0; i < 2; ++i)
            #pragma unroll
            for (int j = 0; j < 2; ++j)
                #pragma unroll
                for (int r = 0; r < 4; ++r) {
                    int row = m0 + wm + i * 16 + qd * 4 + r;
                    int col = n0 + wn + j * 16 + lq;
                    qb[(size_t)row * HID_ + col] = (bf16)acc[i][j][r];
                }
    } else {
        // ---- kv role ----
        const int v = bid - 512;
        const int n0 = (v & 15) * 64, m0 = (v >> 4) * 128;
        f32x4 acc[4][2];
        gemm_core<128, 64>(vfb, wkvb, As, Ws, m0, n0, LDIM_, l, wv, acc);
        const int wm = (wv >> 1) * 64, wn = (wv & 1) * 32;
        if (n0 < HID_) {
            // K-part: plain [n, 2*HID] layout (read by attention staging)
            #pragma unroll
            for (int i = 0; i < 4; ++i)
                #pragma unroll
                for (int j = 0; j < 2; ++j)
                    #pragma unroll
                    for (int r = 0; r < 4; ++r) {
                        int row = m0 + wm + i * 16 + qd * 4 + r;
                        int col = n0 + wn + j * 16 + lq;
                        kvb[(size_t)row * (2 * HID_) + col] = (bf16)acc[i][j][r];
                    }
        } else {
            // V-part: write transposed vT[(b,h,d)][n] via LDS bounce.
            __syncthreads();            // all waves done reading As/Ws
            bf16* T = pool;             // 64 x TST bf16 = 17.4 KB, fits in pool
            #pragma unroll
            for (int i = 0; i < 4; ++i)
                #pragma unroll
                for (int j = 0; j < 2; ++j)
                    #pragma unroll
                    for (int r = 0; r < 4; ++r) {
                        int nl = wm + i * 16 + qd * 4 + r;   // key index 0..127
                        int dl = wn + j * 16 + lq;           // dim index 0..63
                        T[dl * TST + nl] = (bf16)acc[i][j][r];
                    }
            __syncthreads();
            const int b = m0 >> 11, h = (n0 - HID_) >> 6;
            const int nrow0 = m0 & (N_ - 1);
            bf16* dst = vTb + (size_t)((b * H_ + h) * HD_) * N_ + nrow0;
            #pragma unroll
            for (int rep = 0; rep < 4; ++rep) {
                int id = rep * 256 + t;        // 1024 16B chunks: 64 d x 16 c
                int d = id >> 4, c = id & 15;
                bf16x8 val = *(const bf16x8*)&T[d * TST + c * 8];
                *(bf16x8*)&dst[(size_t)d * N_ + c * 8] = val;
            }
        }
    }
}

// ---------------------------------------------------------------------------
// Projection GEMM (2-term split weights): Cf = A @ (Wh+Wl)^T + bias, fp32 out.
// BM=64, BN=64, BK=64. Grid 8x64 = 512 blocks.
// ---------------------------------------------------------------------------
__global__ __launch_bounds__(256)
void gemm_proj(const bf16* __restrict__ A, const bf16* __restrict__ Wh,
               const bf16* __restrict__ Wl, const float* __restrict__ bias,
               float* __restrict__ Cf, int M, int N, int K)
{
    __shared__ bf16 sA[64 * 64];
    __shared__ bf16 sWh[64 * 64], sWl[64 * 64];
    const int t = threadIdx.x, l = t & 63, wv = t >> 6;
    const int n0 = blockIdx.x * 64, m0 = blockIdx.y * 64;
    const int wm = (wv >> 1) * 32, wn = (wv & 1) * 32;
    const int lq = l & 15, qd = l >> 4, swz = l & 7;

    f32x4 acc[2][2];
    #pragma unroll
    for (int i = 0; i < 2; ++i)
        #pragma unroll
        for (int j = 0; j < 2; ++j)
            #pragma unroll
            for (int r = 0; r < 4; ++r) acc[i][j][r] = 0.f;

    for (int kt = 0; kt < K; kt += 64) {
        __syncthreads();
        for (int it = wv; it < 8; it += 4) {
            int r = it * 8 + (l >> 3);
            int c = (l & 7) ^ (r & 7);
            async_cp16(A  + (size_t)(m0 + r) * K + kt + c * 8, &sA[it * 512]);
            size_t go = (size_t)(n0 + r) * K + kt + c * 8;
            async_cp16(Wh + go, &sWh[it * 512]);
            async_cp16(Wl + go, &sWl[it * 512]);
        }
        __syncthreads();
        #pragma unroll
        for (int ks = 0; ks < 2; ++ks) {
            bf16x8 af[2], wh[2], wl[2];
            #pragma unroll
            for (int i = 0; i < 2; ++i) {
                int off = (wm + i * 16 + lq) * 64 + ((ks * 4 + qd) ^ swz) * 8;
                af[i] = *(const bf16x8*)&sA[off];
            }
            #pragma unroll
            for (int j = 0; j < 2; ++j) {
                int off = (wn + j * 16 + lq) * 64 + ((ks * 4 + qd) ^ swz) * 8;
                wh[j] = *(const bf16x8*)&sWh[off];
                wl[j] = *(const bf16x8*)&sWl[off];
            }
            #pragma unroll
            for (int i = 0; i < 2; ++i)
                #pragma unroll
                for (int j = 0; j < 2; ++j) {
                    acc[i][j] = __builtin_amdgcn_mfma_f32_16x16x32_bf16(af[i], wh[j], acc[i][j], 0, 0, 0);
                    acc[i][j] = __builtin_amdgcn_mfma_f32_16x16x32_bf16(af[i], wl[j], acc[i][j], 0, 0, 0);
                }
        }
    }
    #pragma unroll
    for (int i = 0; i < 2; ++i)
        #pragma unroll
        for (int j = 0; j < 2; ++j) {
            int col = n0 + wn + j * 16 + lq;
            float bb = bias[col];
            #pragma unroll
            for (int r = 0; r < 4; ++r) {
                int row = m0 + wm + i * 16 + qd * 4 + r;
                Cf[(size_t)row * N + col] = acc[i][j][r] + bb;
            }
        }
}

// ---------------------------------------------------------------------------
// Flash attention, bf16 MFMA. Block = 64 Q rows (4 waves x 16), KT=64 keys.
// Software-pipelined: K/V double-buffered via global_load_lds, mask prefetched
// one tile ahead into registers (NON-TEMPORAL: 256 MB stream must not evict
// the K/V panels that 16 blocks re-read from L2). End-of-iter sync = counted
// s_waitcnt vmcnt(16) + raw s_barrier: the 16 mask loads for tile t+1 stay in
// flight across the barrier; the 4 oldest retired VMEM ops are this wave's gll.
// ---------------------------------------------------------------------------
#define KT_ 64
#define NT_ 32      // N_/KT_
#define PST 72      // P LDS row stride (bf16)
__global__ __launch_bounds__(256)
void attn_mfma(const bf16* __restrict__ q, const bf16* __restrict__ kv,
               const bf16* __restrict__ vT, const float* __restrict__ mask,
               bf16* __restrict__ ao)
{
    __shared__ bf16 Ks[2][64 * 64];    // [buf][key][dim] chunk-XOR swizzle (16 KB)
    __shared__ bf16 Vs[2][64 * 64];    // [buf][dim][key] chunk-XOR swizzle (16 KB)
    __shared__ bf16 Pa[4][16 * PST];   // per-wave P [qrow][key] (9 KB)
    const int t = threadIdx.x, l = t & 63, wv = t >> 6;
    // XCD-chunked swizzle: 512 blocks = 8 XCDs x 64; each XCD L2 then holds
    // 4 contiguous (b,h) K/V working sets (~2 MB) instead of 32 (16 MB thrash).
    const int bid0 = blockIdx.x;
    const int bid = (bid0 & 7) * 64 + (bid0 >> 3);
    const int lt = bid & 15, h = (bid >> 4) & 7, b = bid >> 7;
    const int l0 = lt * 64;
    const int lq = l & 15, qd = l >> 4, swz = l & 7;
    const int sr = l >> 3;                       // stage: row-in-8 per lane
    const int sc8 = ((l & 7) ^ sr) * 8;          // stage: swizzled chunk offset

    // Q A-fragments (held in regs for all iterations)
    bf16x8 qf[2];
    {
        const bf16* qb = q + (size_t)(b * L_ + l0 + wv * 16 + lq) * HID_ + h * HD_ + qd * 8;
        qf[0] = *(const bf16x8*)qb;
        qf[1] = *(const bf16x8*)(qb + 32);
    }

    f32x4 o[4];
    #pragma unroll
    for (int j = 0; j < 4; ++j)
        #pragma unroll
        for (int r = 0; r < 4; ++r) o[j][r] = 0.f;
    float m_run[4], l_run[4];
    #pragma unroll
    for (int r = 0; r < 4; ++r) { m_run[r] = -1e30f; l_run[r] = 0.f; }

    const bf16* kb = kv + (size_t)(b * N_) * (2 * HID_) + h * HD_;
    const bf16* vb = vT + (size_t)((b * H_ + h) * HD_) * N_;
    const size_t mrow0 = (size_t)((b * H_ + h) * L_ + l0 + wv * 16);
    bf16* Paw = &Pa[wv][0];

    float mkA[4][4], mkB[4][4];

// 4 global_load_lds per wave (2 K + 2 V), issued as the oldest VMEM of the iter
#define STAGE(BUF, NTILE) do {                                                  \
    const int nb_ = (NTILE) * KT_;                                              \
    _Pragma("unroll")                                                           \
    for (int it_ = 0; it_ < 2; ++it_) {                                         \
        int r_ = (wv + it_ * 4) * 8 + sr;                                       \
        async_cp16(kb + (size_t)(nb_ + r_) * (2 * HID_) + sc8,                  \
                   &Ks[BUF][(wv + it_ * 4) * 512]);                             \
    }                                                                           \
    _Pragma("unroll")                                                           \
    for (int it_ = 0; it_ < 2; ++it_) {                                         \
        int r_ = (wv + it_ * 4) * 8 + sr;                                       \
        async_cp16(vb + (size_t)r_ * N_ + nb_ + sc8,                            \
                   &Vs[BUF][(wv + it_ * 4) * 512]);                             \
    }                                                                           \
} while (0)

// 16 dword loads per lane -> registers (C-fragment layout of S), non-temporal
#define MASKLOAD(DST, NTILE) do {                                               \
    const int nb_ = (NTILE) * KT_;                                              \
    _Pragma("unroll")                                                           \
    for (int jj = 0; jj < 4; ++jj)                                              \
        _Pragma("unroll")                                                       \
        for (int r = 0; r < 4; ++r)                                             \
            DST[jj][r] = __builtin_nontemporal_load(                            \
                mask + (mrow0 + qd * 4 + r) * N_ + nb_ + jj * 16 + lq);         \
} while (0)

#define ATTN_ITER(NTI, CB, NB, MKC, MKN) do {                                   \
    if ((NTI) + 1 < NT_) {                                                      \
        STAGE(NB, (NTI) + 1);                                                   \
        __builtin_amdgcn_sched_barrier(0);                                      \
        MASKLOAD(MKN, (NTI) + 1);                                               \
        __builtin_amdgcn_sched_barrier(0);                                      \
    }                                                                           \
    /* S = Q K^T (8 MFMA) on Ks[CB] */                                          \
    f32x4 s[4];                                                                 \
    _Pragma("unroll")                                                           \
    for (int jj = 0; jj < 4; ++jj)                                              \
        _Pragma("unroll")                                                       \
        for (int r = 0; r < 4; ++r) s[jj][r] = 0.f;                             \
    _Pragma("unroll")                                                           \
    for (int ks = 0; ks < 2; ++ks)                                              \
        _Pragma("unroll")                                                       \
        for (int jj = 0; jj < 4; ++jj) {                                        \
            bf16x8 kf = *(const bf16x8*)&Ks[CB][(jj * 16 + lq) * 64 +           \
                                               ((ks * 4 + qd) ^ swz) * 8];      \
            s[jj] = __builtin_amdgcn_mfma_f32_16x16x32_bf16(qf[ks], kf, s[jj], 0, 0, 0); \
        }                                                                       \
    _Pragma("unroll")                                                           \
    for (int jj = 0; jj < 4; ++jj)                                              \
        _Pragma("unroll")                                                       \
        for (int r = 0; r < 4; ++r)                                             \
            s[jj][r] = fmaf(s[jj][r], SCALE_, MKC[jj][r]);                      \
    /* online softmax (row = qd*4+r; reduce over 16 lanes sharing qd) */        \
    float alpha[4], mnew[4];                                                    \
    _Pragma("unroll")                                                           \
    for (int r = 0; r < 4; ++r) {                                               \
        float mx = fmaxf(fmaxf(s[0][r], s[1][r]), fmaxf(s[2][r], s[3][r]));     \
        _Pragma("unroll")                                                       \
        for (int d2 = 1; d2 < 16; d2 <<= 1) mx = fmaxf(mx, __shfl_xor(mx, d2)); \
        mnew[r] = fmaxf(m_run[r], mx);                                          \
        alpha[r] = __expf(m_run[r] - mnew[r]);                                  \
        m_run[r] = mnew[r];                                                     \
    }                                                                           \
    _Pragma("unroll")                                                           \
    for (int r = 0; r < 4; ++r) {                                               \
        float ss = 0.f;                                                         \
        _Pragma("unroll")                                                       \
        for (int jj = 0; jj < 4; ++jj) {                                        \
            float p = __expf(s[jj][r] - mnew[r]);                               \
            Paw[(qd * 4 + r) * PST + jj * 16 + lq] = (bf16)p;                   \
            ss += p;                                                            \
        }                                                                       \
        _Pragma("unroll")                                                       \
        for (int d2 = 1; d2 < 16; d2 <<= 1) ss += __shfl_xor(ss, d2);           \
        l_run[r] = l_run[r] * alpha[r] + ss;                                    \
    }                                                                           \
    asm volatile("s_waitcnt lgkmcnt(0)" ::: "memory");                          \
    __builtin_amdgcn_sched_barrier(0);                                          \
    /* O = O*alpha + P V (8 MFMA) on Vs[CB] */                                  \
    _Pragma("unroll")                                                           \
    for (int jj = 0; jj < 4; ++jj)                                              \
        _Pragma("unroll")                                                       \
        for (int r = 0; r < 4; ++r) o[jj][r] *= alpha[r];                       \
    _Pragma("unroll")                                                           \
    for (int ks = 0; ks < 2; ++ks) {                                            \
        bf16x8 pf = *(const bf16x8*)&Paw[lq * PST + ks * 32 + qd * 8];          \
        _Pragma("unroll")                                                       \
        for (int jj = 0; jj < 4; ++jj) {                                        \
            bf16x8 vf = *(const bf16x8*)&Vs[CB][(jj * 16 + lq) * 64 +           \
                                               ((ks * 4 + qd) ^ swz) * 8];      \
            o[jj] = __builtin_amdgcn_mfma_f32_16x16x32_bf16(pf, vf, o[jj], 0, 0, 0); \
        }                                                                       \
    }                                                                           \
    /* end-of-iter: own stage(nxt) done (mask loads stay in flight), waves sync */ \
    __builtin_amdgcn_sched_barrier(0);                                          \
    asm volatile("s_waitcnt vmcnt(16)" ::: "memory");                           \
    __builtin_amdgcn_s_barrier();                                               \
    __builtin_amdgcn_sched_barrier(0);                                          \
} while (0)

    // prologue: stage tile 0 into buf 0, mask tile 0 into mkA
    STAGE(0, 0);
    MASKLOAD(mkA, 0);
    __syncthreads();

    #pragma unroll 1
    for (int nt2 = 0; nt2 < NT_; nt2 += 2) {
        ATTN_ITER(nt2,     0, 1, mkA, mkB);
        ATTN_ITER(nt2 + 1, 1, 0, mkB, mkA);
    }
#undef ATTN_ITER
#undef MASKLOAD
#undef STAGE

    // epilogue: normalize + plain bf16 store
    #pragma unroll
    for (int jj = 0; jj < 4; ++jj)
        #pragma unroll
        for (int r = 0; r < 4; ++r) {
            int row = b * L_ + l0 + wv * 16 + qd * 4 + r;
            int col = h * HD_ + jj * 16 + lq;
            ao[(size_t)row * HID_ + col] = (bf16)(o[jj][r] / l_run[r]);
        }
}

// ---------------------------------------------------------------------------
extern "C" void kernel_launch(void* const* d_in, const int* in_sizes, int n_in,
                              void* d_out, int out_size, void* d_ws, size_t ws_size,
                              hipStream_t stream)
{
    const float* x      = (const float*)d_in[0];  // [B,L,VDIM]
    const float* vfeats = (const float*)d_in[1];  // [B,N,LDIM]
    const float* mask   = (const float*)d_in[2];  // [B,H,L,N]
    const float* Wq     = (const float*)d_in[3];  // [HID,VDIM]
    const float* Wkv    = (const float*)d_in[4];  // [2*HID,LDIM]
    const float* Wproj  = (const float*)d_in[5];  // [VDIM,HID]
    const float* bproj  = (const float*)d_in[6];  // [VDIM]
    float* out = (float*)d_out;                   // [B,L,VDIM] fp32

    // Workspace layout (~53.5 MB, no aliasing)
    char* ws = (char*)d_ws;
    bf16* xb   = (bf16*)(ws);                     // 4 MB
    bf16* vfb  = (bf16*)(ws + 4194304);           // 12 MB
    bf16* wqb  = (bf16*)(ws + 16777216);          // 0.5 MB
    bf16* wkvb = (bf16*)(ws + 17301504);          // 1.5 MB
    bf16* wph  = (bf16*)(ws + 18874368);          // 0.5 MB
    bf16* wpl  = (bf16*)(ws + 19398656);          // 0.5 MB
    bf16* qb   = (bf16*)(ws + 19922944);          // 4 MB
    bf16* kvb  = (bf16*)(ws + 24117248);          // 16 MB (K-part written only)
    bf16* vTb  = (bf16*)(ws + 40894464);          // 8 MB
    bf16* aob  = (bf16*)(ws + 49283072);          // 4 MB

    dim3 blk(256);
    // fused converts (1 launch)
    cvt_all<<<dim3((XE_ + VFE_ + WQE_ + WKVE_ + WPE_) / 1024), blk, 0, stream>>>(
        x, vfeats, Wq, Wkv, Wproj, xb, vfb, wqb, wkvb, wph, wpl);
    // fused q-GEMM (512 blocks, 64x64) + kv-GEMM (1024 blocks, 128x64) with
    // in-epilogue V transpose: 1536 blocks, one launch
    gemm_qkv<<<dim3(1536), blk, 0, stream>>>(xb, wqb, qb, vfb, wkvb, kvb, vTb);
    // attention (512 blocks, pipelined, NT mask stream)
    attn_mfma<<<dim3(B_ * H_ * (L_ / 64)), blk, 0, stream>>>(qb, kvb, vTb, mask, aob);
    // out = attn_out @ (Wproj hi+lo)^T + bproj   grid 8x64 = 512 blocks
    gemm_proj<<<dim3(VDIM_ / 64, B_ * L_ / 64), blk, 0, stream>>>(
        aob, wph, wpl, bproj, out, B_ * L_, VDIM_, HID_);
}